// Round 10
// baseline (242.377 us; speedup 1.0000x reference)
//
#include <hip/hip_runtime.h>
#include <stdint.h>

// Problem constants
#define CC    1024
#define EE    320
#define KN    640         // G*E
#define DD    256
#define MTOT  16384       // B*T
#define NBLK  1280        // GEMM grid: 128 m-tiles(128) x 10 n-tiles(64)
#define OUT4  2097152     // output float4 count
#define MARGIN 2.0f       // candidate gate: ~60 sigma of hi*hi dropped-term error

typedef __attribute__((ext_vector_type(8))) short short8;
typedef __attribute__((ext_vector_type(4))) float f32x4;

__device__ __forceinline__ unsigned int f32_orderable(float x) {
    unsigned int b = __float_as_uint(x);
    return (b & 0x80000000u) ? ~b : (b | 0x80000000u);
}

__device__ __forceinline__ unsigned short bf16_rne(float x) {
    unsigned int u = __float_as_uint(x);
    return (unsigned short)((u + 0x7FFFu + ((u >> 16) & 1u)) >> 16);
}

__device__ __forceinline__ short8 cvt_hi8(float4 a, float4 b) {
    short8 h;
    h[0] = (short)bf16_rne(a.x); h[1] = (short)bf16_rne(a.y);
    h[2] = (short)bf16_rne(a.z); h[3] = (short)bf16_rne(a.w);
    h[4] = (short)bf16_rne(b.x); h[5] = (short)bf16_rne(b.y);
    h[6] = (short)bf16_rne(b.z); h[7] = (short)bf16_rne(b.w);
    return h;
}

__global__ void init_slots_kernel(unsigned long long* __restrict__ slots) {
    if (threadIdx.x < 17) slots[threadIdx.x] = 0ull;
}

// ------------------- prep: zero-fill out + W -> fragment-major B2F + slot init -------------
// B2F layout: unit = nTile*32 + kc;  B2F[unit*512 + lane*8 + j] =
//   bf16_hi of W[nTile*16 + (lane&15)][kc*32 + (lane>>4)*8 + j]
__global__ __launch_bounds__(256)
void prep_kernel(const float* __restrict__ W, unsigned short* __restrict__ B2F,
                 unsigned long long* __restrict__ slots, float* __restrict__ out) {
    const int bid = blockIdx.x;     // 2048 blocks
    const int tid = threadIdx.x;
    // zero-fill: 4 float4 per thread covers 2,097,152 exactly
    f32x4 z = {0.f, 0.f, 0.f, 0.f};
#pragma unroll
    for (int ps = 0; ps < 4; ps++) {
        int zidx = ps * (2048 * 256) + bid * 256 + tid;
        __builtin_nontemporal_store(z, (f32x4*)out + zidx);
    }
    if (bid == 0 && tid < 17) slots[tid] = 0ull;   // 16 slots + counter
    if (bid < 320) {                                // W: 1280 units, 4 per block
        int unit = bid * 4 + (tid >> 6);
        int lane = tid & 63;
        int rt = unit >> 5, kc = unit & 31;
        int row = rt * 16 + (lane & 15);
        int col = kc * 32 + ((lane >> 4) << 3);
        const float* p = W + (size_t)row * CC + col;
        float4 v0 = *(const float4*)p;
        float4 v1 = *(const float4*)(p + 4);
        *(short8*)(B2F + (size_t)unit * 512 + lane * 8) = cvt_hi8(v0, v1);
    }
}

// ------------------- 1-pass bf16 MFMA GEMM + margin argmax + exact refine + scatter ----------
// approx C = Xhi * Whi^T. A loaded DIRECTLY from fp32 X (16x128B segments/wave),
// converted to bf16-hi in-register; B from fragment-major B2F. No LDS, no K-loop
// barriers; 1-ahead register pipeline + 5 blocks/CU for latency hiding.
// Tile: block 128m x 64n; wave 32m x 64n (unique A rows per wave -> no dup A loads).
__global__ __launch_bounds__(256, 4)
void gemm_argmax_mfma(const float* __restrict__ X,
                      const unsigned short* __restrict__ B2F,
                      const float* __restrict__ W,
                      const float* __restrict__ bias,
                      const float* __restrict__ codebook,
                      float* __restrict__ out,
                      unsigned long long* __restrict__ slots,
                      unsigned int* __restrict__ counter) {
    __shared__ float redf[4];
    __shared__ int cnt_s;
    __shared__ int cand_s[128];
    __shared__ unsigned int done_s;
    __shared__ unsigned long long s16[16];

    const int tid  = threadIdx.x;
    const int lane = tid & 63;
    const int wave = tid >> 6;

    // XCD swizzle: one XCD covers 16 m-tiles x all 10 n-tiles (n fastest) -> X L2 reuse.
    const int l   = blockIdx.x;        // 0..1279
    const int xcd = l & 7;
    const int w   = l >> 3;            // 0..159
    const int mt  = xcd * 16 + w / 10; // 0..127
    const int nt  = w % 10;            // 0..9
    const int m0 = mt * 128;
    const int n0 = nt * 64;

    const int rb = m0 + wave * 32;     // wave's 32 A rows (unique per wave)
    const int fr = lane & 15;
    const int q  = lane >> 4;

    // A source: lane reads X[rb + ti*16 + fr][q*8 .. q*8+8) as 2 float4 (32B)
    const float* Axp[2];
#pragma unroll
    for (int ti = 0; ti < 2; ti++)
        Axp[ti] = X + (size_t)(rb + ti * 16 + fr) * CC + q * 8;
    // B source: fragment-major, kc stride 512 shorts
    const unsigned short* Bxp[4];
#pragma unroll
    for (int tj = 0; tj < 4; tj++)
        Bxp[tj] = B2F + ((size_t)((n0 >> 4) + tj) * 32) * 512 + lane * 8;

    f32x4 acc[2][4] = {};
    float4 af0[2][2], af1[2][2];
    short8 bb0[4], bb1[4];

    // prologue: load it=0 operands
#pragma unroll
    for (int ti = 0; ti < 2; ti++) {
        af0[ti][0] = *(const float4*)(Axp[ti]);
        af0[ti][1] = *(const float4*)(Axp[ti] + 4);
        Axp[ti] += 32;
    }
#pragma unroll
    for (int tj = 0; tj < 4; tj++) {
        bb0[tj] = *(const short8*)(Bxp[tj]);
        Bxp[tj] += 512;
    }

#define STEP(CURA, CURB, NXTA, NXTB, IT)                                         \
    {                                                                            \
        if ((IT) < 31) {                                                         \
            _Pragma("unroll")                                                    \
            for (int ti = 0; ti < 2; ti++) {                                     \
                NXTA[ti][0] = *(const float4*)(Axp[ti]);                         \
                NXTA[ti][1] = *(const float4*)(Axp[ti] + 4);                     \
                Axp[ti] += 32;                                                   \
            }                                                                    \
            _Pragma("unroll")                                                    \
            for (int tj = 0; tj < 4; tj++) {                                     \
                NXTB[tj] = *(const short8*)(Bxp[tj]);                            \
                Bxp[tj] += 512;                                                  \
            }                                                                    \
        }                                                                        \
        short8 ah[2];                                                            \
        _Pragma("unroll")                                                        \
        for (int ti = 0; ti < 2; ti++) ah[ti] = cvt_hi8(CURA[ti][0], CURA[ti][1]); \
        _Pragma("unroll")                                                        \
        for (int ti = 0; ti < 2; ti++)                                           \
            _Pragma("unroll")                                                    \
            for (int tj = 0; tj < 4; tj++)                                       \
                acc[ti][tj] = __builtin_amdgcn_mfma_f32_16x16x32_bf16(           \
                    ah[ti], CURB[tj], acc[ti][tj], 0, 0, 0);                     \
    }

    for (int it2 = 0; it2 < 16; it2++) {
        STEP(af0, bb0, af1, bb1, it2 * 2)
        STEP(af1, bb1, af0, bb0, it2 * 2 + 1)
    }
#undef STEP

    // ---- epilogue: block max of approx logits ----
    // C/D layout (16x16x32): col = lane&15, row = (lane>>4)*4 + reg
    float bias4[4];
#pragma unroll
    for (int tj = 0; tj < 4; tj++) bias4[tj] = bias[n0 + tj * 16 + (lane & 15)];

    float vmax = -3.0e38f;
#pragma unroll
    for (int ti = 0; ti < 2; ti++)
#pragma unroll
        for (int tj = 0; tj < 4; tj++)
#pragma unroll
            for (int r = 0; r < 4; r++)
                vmax = fmaxf(vmax, acc[ti][tj][r] + bias4[tj]);
#pragma unroll
    for (int off = 32; off > 0; off >>= 1)
        vmax = fmaxf(vmax, __shfl_down(vmax, off, 64));
    if (lane == 0) redf[wave] = vmax;
    if (tid == 0) cnt_s = 0;
    __syncthreads();
    float bm = fmaxf(fmaxf(redf[0], redf[1]), fmaxf(redf[2], redf[3]));
    float thresh = bm - MARGIN;

    // ---- collect candidates within MARGIN of block max ----
#pragma unroll
    for (int ti = 0; ti < 2; ti++) {
#pragma unroll
        for (int r = 0; r < 4; r++) {
            int m = rb + ti * 16 + (lane >> 4) * 4 + r;
#pragma unroll
            for (int tj = 0; tj < 4; tj++) {
                float v = acc[ti][tj][r] + bias4[tj];
                if (v >= thresh) {
                    int n = n0 + tj * 16 + (lane & 15);
                    int idx = atomicAdd(&cnt_s, 1);
                    if (idx < 128) cand_s[idx] = (m << 10) | n;
                }
            }
        }
    }
    __syncthreads();
    int cnt = cnt_s < 128 ? cnt_s : 128;

    // ---- exact fp32 refine of each candidate (cooperative 1024-dot) ----
    for (int i = 0; i < cnt; i++) {
        int mc = cand_s[i] >> 10;
        int nc = cand_s[i] & 1023;
        float4 xv = *(const float4*)(X + (size_t)mc * CC + tid * 4);
        float4 wv = *(const float4*)(W + (size_t)nc * CC + tid * 4);
        float p = xv.x * wv.x + xv.y * wv.y + xv.z * wv.z + xv.w * wv.w;
#pragma unroll
        for (int off = 32; off > 0; off >>= 1) p += __shfl_down(p, off, 64);
        if (lane == 0) redf[wave] = p;
        __syncthreads();
        if (tid == 0) {
            float tot = redf[0] + redf[1] + redf[2] + redf[3] + bias[nc];
            unsigned int c = (unsigned int)((mc & 1023) * KN + nc);
            unsigned long long pk =
                ((unsigned long long)f32_orderable(tot) << 32) |
                (unsigned long long)(~c);
            atomicMax(slots + (mc >> 10), pk);
        }
        __syncthreads();
    }

    if (tid == 0) {
        __threadfence();
        done_s = atomicAdd(counter, 1u);
    }
    __syncthreads();

    // ---- last block scatters the 16 codebook rows ----
    if (done_s == NBLK - 1) {
        if (tid < 16) s16[tid] = atomicAdd(slots + tid, 0ull);   // coherent cross-XCD read
        __syncthreads();
        int rr  = tid >> 4;
        int seg = tid & 15;
        unsigned long long p = s16[rr];
        unsigned int c = ~(unsigned int)(p & 0xFFFFFFFFull);
        int tl = (int)(c / KN);
        int kg = (int)(c % KN);
        int b  = rr >> 1, h = rr & 1;
        int nstar = b * 2048 + h * 1024 + tl;
        int g = kg / EE;
        const float4* src = (const float4*)(codebook + (size_t)kg * DD) + seg * 4;
        float4* dst = (float4*)(out + (size_t)nstar * 512 + (size_t)g * DD) + seg * 4;
#pragma unroll
        for (int j = 0; j < 4; j++) dst[j] = src[j];
    }
}

// ------------------- fallback-only kernels (ws too small; not used in practice) ------------
__global__ __launch_bounds__(256)
void zs_kernel(const unsigned long long* __restrict__ slots,
               const float* __restrict__ codebook,
               float4* __restrict__ out4) {
    int i4 = blockIdx.x * 256 + threadIdx.x;
    int n  = i4 >> 7;
    int c4 = i4 & 127;
    int b  = n >> 11;
    int h  = (n >> 10) & 1;
    unsigned long long p = slots[b * 2 + h];
    unsigned int c = ~(unsigned int)(p & 0xFFFFFFFFull);
    int tl = (int)(c / KN);
    int kg = (int)(c % KN);
    int nstar = b * 2048 + h * 1024 + tl;
    int g = kg / EE;
    float4 v = make_float4(0.f, 0.f, 0.f, 0.f);
    if (n == nstar && (c4 >> 6) == g)
        v = ((const float4*)codebook)[kg * 64 + (c4 & 63)];
    out4[i4] = v;
}

#define BM 128
#define BN 64
#define BK 32
#define LDA (BM + 4)
#define LDB (BN + 4)

__global__ __launch_bounds__(128)
void gemm_argmax_f32(const float* __restrict__ X, const float* __restrict__ W,
                     const float* __restrict__ bias,
                     unsigned long long* __restrict__ slots) {
    __shared__ float Asf[BK][LDA];
    __shared__ float Bsf[BK][LDB];
    const int tid = threadIdx.x;
    const int m0 = blockIdx.y * BM;
    const int n0 = blockIdx.x * BN;
    const int tx = tid & 7, ty = tid >> 3;
    float acc[8][8];
#pragma unroll
    for (int i = 0; i < 8; i++)
#pragma unroll
        for (int j = 0; j < 8; j++) acc[i][j] = 0.0f;
    const int lm = tid >> 3, lk = (tid & 7) * 4;
    const float* Xb = X + (size_t)m0 * CC;
    const float* Wb = W + (size_t)n0 * CC;
    for (int k0 = 0; k0 < CC; k0 += BK) {
#pragma unroll
        for (int r = 0; r < 8; r++) {
            int m = r * 16 + lm;
            float4 v = *(const float4*)(Xb + (size_t)m * CC + k0 + lk);
            Asf[lk + 0][m] = v.x; Asf[lk + 1][m] = v.y; Asf[lk + 2][m] = v.z; Asf[lk + 3][m] = v.w;
        }
#pragma unroll
        for (int r = 0; r < 4; r++) {
            int m = r * 16 + lm;
            float4 v = *(const float4*)(Wb + (size_t)m * CC + k0 + lk);
            Bsf[lk + 0][m] = v.x; Bsf[lk + 1][m] = v.y; Bsf[lk + 2][m] = v.z; Bsf[lk + 3][m] = v.w;
        }
        __syncthreads();
#pragma unroll
        for (int kk = 0; kk < BK; kk++) {
            float4 A0 = *(const float4*)&Asf[kk][ty * 8];
            float4 A1 = *(const float4*)&Asf[kk][ty * 8 + 4];
            float4 B0 = *(const float4*)&Bsf[kk][tx * 8];
            float4 B1 = *(const float4*)&Bsf[kk][tx * 8 + 4];
            float a[8] = {A0.x, A0.y, A0.z, A0.w, A1.x, A1.y, A1.z, A1.w};
            float b[8] = {B0.x, B0.y, B0.z, B0.w, B1.x, B1.y, B1.z, B1.w};
#pragma unroll
            for (int i = 0; i < 8; i++)
#pragma unroll
                for (int j = 0; j < 8; j++) acc[i][j] = fmaf(a[i], b[j], acc[i][j]);
        }
        __syncthreads();
    }
    unsigned long long best = 0ull;
#pragma unroll
    for (int i = 0; i < 8; i++) {
        int mg = m0 + ty * 8 + i;
        int tl = mg & 1023;
#pragma unroll
        for (int j = 0; j < 8; j++) {
            int kg = n0 + tx * 8 + j;
            float v = acc[i][j] + bias[kg];
            unsigned int c = (unsigned int)(tl * KN + kg);
            unsigned long long p = ((unsigned long long)f32_orderable(v) << 32) |
                                   (unsigned long long)(~c);
            if (p > best) best = p;
        }
    }
#pragma unroll
    for (int off = 32; off > 0; off >>= 1) {
        unsigned long long o = __shfl_down(best, off, 64);
        if (o > best) best = o;
    }
    __shared__ unsigned long long red2[2];
    if ((tid & 63) == 0) red2[tid >> 6] = best;
    __syncthreads();
    if (tid == 0) {
        unsigned long long b0 = red2[0], b1 = red2[1];
        atomicMax(slots + (m0 >> 10), b0 > b1 ? b0 : b1);
    }
}

extern "C" void kernel_launch(void* const* d_in, const int* in_sizes, int n_in,
                              void* d_out, int out_size, void* d_ws, size_t ws_size,
                              hipStream_t stream) {
    const float* X        = (const float*)d_in[0];  // (8,2048,1024)
    const float* W        = (const float*)d_in[1];  // (640,1024)
    const float* bias     = (const float*)d_in[2];  // (640,)
    const float* codebook = (const float*)d_in[3];  // (640,256)
    float* out = (float*)d_out;                     // (8,2048,512) fp32

    unsigned long long* slots = (unsigned long long*)d_ws;   // [0..15] slots, [16] counter
    unsigned int* counter = (unsigned int*)(slots + 16);
    const size_t B_off   = 256;
    const size_t B_bytes = (size_t)KN * CC * 2;     // 1,310,720 (hi-only frag-major W)
    const size_t need = B_off + B_bytes;

    if (ws_size >= need) {
        unsigned short* B2F = (unsigned short*)((char*)d_ws + B_off);
        hipLaunchKernelGGL(prep_kernel, dim3(2048), dim3(256), 0, stream,
                           W, B2F, slots, out);
        hipLaunchKernelGGL(gemm_argmax_mfma, dim3(NBLK), dim3(256), 0, stream,
                           X, B2F, W, bias, codebook, out, slots, counter);
    } else {
        hipLaunchKernelGGL(init_slots_kernel, dim3(1), dim3(64), 0, stream, slots);
        hipLaunchKernelGGL(gemm_argmax_f32, dim3(KN / BN, MTOT / BM), dim3(128), 0, stream,
                           X, W, bias, slots);
        hipLaunchKernelGGL(zs_kernel, dim3(OUT4 / 256), dim3(256), 0, stream,
                           slots, codebook, (float4*)out);
    }
}

// Round 11
// 186.012 us; speedup vs baseline: 1.3030x; 1.3030x over previous
//
#include <hip/hip_runtime.h>
#include <stdint.h>

// Problem constants
#define CC    1024
#define EE    320
#define KN    640         // G*E
#define DD    256
#define MTOT  16384       // B*T
#define NBLK  1280        // GEMM grid: 128 m-tiles(128) x 10 n-tiles(64)
#define OUT4  2097152     // output float4 count
#define MARGIN 2.0f       // candidate gate: ~30 sigma of hi*hi dropped-term error

typedef __attribute__((ext_vector_type(8))) short short8;
typedef __attribute__((ext_vector_type(4))) float f32x4;

__device__ __forceinline__ unsigned int f32_orderable(float x) {
    unsigned int b = __float_as_uint(x);
    return (b & 0x80000000u) ? ~b : (b | 0x80000000u);
}

__device__ __forceinline__ unsigned short bf16_rne(float x) {
    unsigned int u = __float_as_uint(x);
    return (unsigned short)((u + 0x7FFFu + ((u >> 16) & 1u)) >> 16);
}

__global__ void init_slots_kernel(unsigned long long* __restrict__ slots) {
    if (threadIdx.x < 17) slots[threadIdx.x] = 0ull;
}

// ------------------- fused convert (hi-only) + zero-fill + slot init -------------------
// Fragment-major hi-only layout (A2F from X, B2F from W):
//   unit = rowTile*32 + kc   (rowTile = row/16, kc = k/32)
//   buf[unit*512 + lane*8 + j] = bf16_hi of M[rowTile*16 + (lane&15)][kc*32 + (lane>>4)*8 + j]
// -> GEMM frag load = base + lane*16B (coalesced 1KB/wave, exact 16x16x32 operand layout).
__global__ __launch_bounds__(256)
void convert_kernel(const float* __restrict__ X, const float* __restrict__ W,
                    unsigned short* __restrict__ A2F, unsigned short* __restrict__ B2F,
                    unsigned long long* __restrict__ slots, float* __restrict__ out) {
    const int bid = blockIdx.x;
    const int tid = threadIdx.x;
    {   // zero-fill share of output (blocks 0..8191 cover all 2,097,152 float4s)
        int zidx = bid * 256 + tid;
        f32x4 z = {0.f, 0.f, 0.f, 0.f};
        if (zidx < OUT4) __builtin_nontemporal_store(z, (f32x4*)out + zidx);
    }
    const int lane = tid & 63;
    const float* src;
    unsigned short* dst;
    int unit;
    if (bid < 8192) {                      // X: units = 1024 mb x 32 kc
        unit = bid * 4 + (tid >> 6);
        src = X; dst = A2F;
    } else {                               // W: 1280 units -> 320 blocks
        if (bid == 8192 && tid < 17) slots[tid] = 0ull;   // 16 slots + counter
        unit = (bid - 8192) * 4 + (tid >> 6);
        src = W; dst = B2F;
    }
    int rt = unit >> 5, kc = unit & 31;
    int row = rt * 16 + (lane & 15);
    int col = kc * 32 + ((lane >> 4) << 3);
    const float* p = src + (size_t)row * CC + col;
    float4 v0 = *(const float4*)p;
    float4 v1 = *(const float4*)(p + 4);
    short8 hi;
    hi[0] = (short)bf16_rne(v0.x); hi[1] = (short)bf16_rne(v0.y);
    hi[2] = (short)bf16_rne(v0.z); hi[3] = (short)bf16_rne(v0.w);
    hi[4] = (short)bf16_rne(v1.x); hi[5] = (short)bf16_rne(v1.y);
    hi[6] = (short)bf16_rne(v1.z); hi[7] = (short)bf16_rne(v1.w);
    *(short8*)(dst + (size_t)unit * 512 + lane * 8) = hi;
}

// ------------------- 1-pass bf16 MFMA GEMM + margin argmax + exact refine + scatter ----------
// approx C = Xhi * Whi^T (dropped-term error sigma ~0.067; margin 2.0 = ~30 sigma).
// A AND B both from fragment-major ws arrays (pre-converted; R9-proven pipeline shape).
// No LDS, no K-loop barriers; 1-ahead register pipeline.
// Tile: block 128m x 64n (grid 1280 -> 4-5 blocks/CU); wave 32m x 64n.
__global__ __launch_bounds__(256, 4)
void gemm_argmax_mfma(const unsigned short* __restrict__ A2F,
                      const unsigned short* __restrict__ B2F,
                      const float* __restrict__ X,
                      const float* __restrict__ W,
                      const float* __restrict__ bias,
                      const float* __restrict__ codebook,
                      float* __restrict__ out,
                      unsigned long long* __restrict__ slots,
                      unsigned int* __restrict__ counter) {
    __shared__ float redf[4];
    __shared__ int cnt_s;
    __shared__ int cand_s[128];
    __shared__ unsigned int done_s;
    __shared__ unsigned long long s16[16];

    const int tid  = threadIdx.x;
    const int lane = tid & 63;
    const int wave = tid >> 6;

    // XCD swizzle: one XCD covers 16 m-tiles x all 10 n-tiles (n fastest) -> A2F L2 reuse.
    const int l   = blockIdx.x;        // 0..1279
    const int xcd = l & 7;
    const int w   = l >> 3;            // 0..159
    const int mt  = xcd * 16 + w / 10; // 0..127
    const int nt  = w % 10;            // 0..9
    const int m0 = mt * 128;
    const int n0 = nt * 64;

    const int rb = m0 + wave * 32;     // wave's 32 A rows (unique per wave)

    // frag pointers: kc stride = 512 shorts (hi-only, fragment-major)
    const unsigned short* Ap[2];
    const unsigned short* Bp[4];
#pragma unroll
    for (int ti = 0; ti < 2; ti++)
        Ap[ti] = A2F + ((size_t)((rb >> 4) + ti) * 32) * 512 + lane * 8;
#pragma unroll
    for (int tj = 0; tj < 4; tj++)
        Bp[tj] = B2F + ((size_t)((n0 >> 4) + tj) * 32) * 512 + lane * 8;

    f32x4 acc[2][4] = {};
    short8 a0[2], b0[4], a1[2], b1[4];

    // prologue: load it=0 frags
#pragma unroll
    for (int ti = 0; ti < 2; ti++) { a0[ti] = *(const short8*)(Ap[ti]); Ap[ti] += 512; }
#pragma unroll
    for (int tj = 0; tj < 4; tj++) { b0[tj] = *(const short8*)(Bp[tj]); Bp[tj] += 512; }

#define STEP(CURA, CURB, NXTA, NXTB, IT)                                         \
    {                                                                            \
        if ((IT) < 31) {                                                         \
            _Pragma("unroll")                                                    \
            for (int ti = 0; ti < 2; ti++) {                                     \
                NXTA[ti] = *(const short8*)(Ap[ti]); Ap[ti] += 512;              \
            }                                                                    \
            _Pragma("unroll")                                                    \
            for (int tj = 0; tj < 4; tj++) {                                     \
                NXTB[tj] = *(const short8*)(Bp[tj]); Bp[tj] += 512;              \
            }                                                                    \
        }                                                                        \
        _Pragma("unroll")                                                        \
        for (int ti = 0; ti < 2; ti++)                                           \
            _Pragma("unroll")                                                    \
            for (int tj = 0; tj < 4; tj++)                                       \
                acc[ti][tj] = __builtin_amdgcn_mfma_f32_16x16x32_bf16(           \
                    CURA[ti], CURB[tj], acc[ti][tj], 0, 0, 0);                   \
    }

    for (int it2 = 0; it2 < 16; it2++) {
        STEP(a0, b0, a1, b1, it2 * 2)
        STEP(a1, b1, a0, b0, it2 * 2 + 1)
    }
#undef STEP

    // ---- epilogue: block max of approx logits ----
    // C/D layout (16x16x32): col = lane&15, row = (lane>>4)*4 + reg
    float bias4[4];
#pragma unroll
    for (int tj = 0; tj < 4; tj++) bias4[tj] = bias[n0 + tj * 16 + (lane & 15)];

    float vmax = -3.0e38f;
#pragma unroll
    for (int ti = 0; ti < 2; ti++)
#pragma unroll
        for (int tj = 0; tj < 4; tj++)
#pragma unroll
            for (int r = 0; r < 4; r++)
                vmax = fmaxf(vmax, acc[ti][tj][r] + bias4[tj]);
#pragma unroll
    for (int off = 32; off > 0; off >>= 1)
        vmax = fmaxf(vmax, __shfl_down(vmax, off, 64));
    if (lane == 0) redf[wave] = vmax;
    if (tid == 0) cnt_s = 0;
    __syncthreads();
    float bm = fmaxf(fmaxf(redf[0], redf[1]), fmaxf(redf[2], redf[3]));
    float thresh = bm - MARGIN;

    // ---- collect candidates within MARGIN of block max ----
#pragma unroll
    for (int ti = 0; ti < 2; ti++) {
#pragma unroll
        for (int r = 0; r < 4; r++) {
            int m = rb + ti * 16 + (lane >> 4) * 4 + r;
#pragma unroll
            for (int tj = 0; tj < 4; tj++) {
                float v = acc[ti][tj][r] + bias4[tj];
                if (v >= thresh) {
                    int n = n0 + tj * 16 + (lane & 15);
                    int idx = atomicAdd(&cnt_s, 1);
                    if (idx < 128) cand_s[idx] = (m << 10) | n;
                }
            }
        }
    }
    __syncthreads();
    int cnt = cnt_s < 128 ? cnt_s : 128;

    // ---- exact fp32 refine of each candidate (cooperative 1024-dot) ----
    for (int i = 0; i < cnt; i++) {
        int mc = cand_s[i] >> 10;
        int nc = cand_s[i] & 1023;
        float4 xv = *(const float4*)(X + (size_t)mc * CC + tid * 4);
        float4 wv = *(const float4*)(W + (size_t)nc * CC + tid * 4);
        float p = xv.x * wv.x + xv.y * wv.y + xv.z * wv.z + xv.w * wv.w;
#pragma unroll
        for (int off = 32; off > 0; off >>= 1) p += __shfl_down(p, off, 64);
        if (lane == 0) redf[wave] = p;
        __syncthreads();
        if (tid == 0) {
            float tot = redf[0] + redf[1] + redf[2] + redf[3] + bias[nc];
            unsigned int c = (unsigned int)((mc & 1023) * KN + nc);
            unsigned long long pk =
                ((unsigned long long)f32_orderable(tot) << 32) |
                (unsigned long long)(~c);
            atomicMax(slots + (mc >> 10), pk);
        }
        __syncthreads();
    }

    if (tid == 0) {
        __threadfence();
        done_s = atomicAdd(counter, 1u);
    }
    __syncthreads();

    // ---- last block scatters the 16 codebook rows ----
    if (done_s == NBLK - 1) {
        if (tid < 16) s16[tid] = atomicAdd(slots + tid, 0ull);   // coherent cross-XCD read
        __syncthreads();
        int rr  = tid >> 4;
        int seg = tid & 15;
        unsigned long long p = s16[rr];
        unsigned int c = ~(unsigned int)(p & 0xFFFFFFFFull);
        int tl = (int)(c / KN);
        int kg = (int)(c % KN);
        int b  = rr >> 1, h = rr & 1;
        int nstar = b * 2048 + h * 1024 + tl;
        int g = kg / EE;
        const float4* src = (const float4*)(codebook + (size_t)kg * DD) + seg * 4;
        float4* dst = (float4*)(out + (size_t)nstar * 512 + (size_t)g * DD) + seg * 4;
#pragma unroll
        for (int j = 0; j < 4; j++) dst[j] = src[j];
    }
}

// ------------------- fallback-only kernels (ws too small; not used in practice) ------------
__global__ __launch_bounds__(256)
void zs_kernel(const unsigned long long* __restrict__ slots,
               const float* __restrict__ codebook,
               float4* __restrict__ out4) {
    int i4 = blockIdx.x * 256 + threadIdx.x;
    int n  = i4 >> 7;
    int c4 = i4 & 127;
    int b  = n >> 11;
    int h  = (n >> 10) & 1;
    unsigned long long p = slots[b * 2 + h];
    unsigned int c = ~(unsigned int)(p & 0xFFFFFFFFull);
    int tl = (int)(c / KN);
    int kg = (int)(c % KN);
    int nstar = b * 2048 + h * 1024 + tl;
    int g = kg / EE;
    float4 v = make_float4(0.f, 0.f, 0.f, 0.f);
    if (n == nstar && (c4 >> 6) == g)
        v = ((const float4*)codebook)[kg * 64 + (c4 & 63)];
    out4[i4] = v;
}

#define BM 128
#define BN 64
#define BK 32
#define LDA (BM + 4)
#define LDB (BN + 4)

__global__ __launch_bounds__(128)
void gemm_argmax_f32(const float* __restrict__ X, const float* __restrict__ W,
                     const float* __restrict__ bias,
                     unsigned long long* __restrict__ slots) {
    __shared__ float Asf[BK][LDA];
    __shared__ float Bsf[BK][LDB];
    const int tid = threadIdx.x;
    const int m0 = blockIdx.y * BM;
    const int n0 = blockIdx.x * BN;
    const int tx = tid & 7, ty = tid >> 3;
    float acc[8][8];
#pragma unroll
    for (int i = 0; i < 8; i++)
#pragma unroll
        for (int j = 0; j < 8; j++) acc[i][j] = 0.0f;
    const int lm = tid >> 3, lk = (tid & 7) * 4;
    const float* Xb = X + (size_t)m0 * CC;
    const float* Wb = W + (size_t)n0 * CC;
    for (int k0 = 0; k0 < CC; k0 += BK) {
#pragma unroll
        for (int r = 0; r < 8; r++) {
            int m = r * 16 + lm;
            float4 v = *(const float4*)(Xb + (size_t)m * CC + k0 + lk);
            Asf[lk + 0][m] = v.x; Asf[lk + 1][m] = v.y; Asf[lk + 2][m] = v.z; Asf[lk + 3][m] = v.w;
        }
#pragma unroll
        for (int r = 0; r < 4; r++) {
            int m = r * 16 + lm;
            float4 v = *(const float4*)(Wb + (size_t)m * CC + k0 + lk);
            Bsf[lk + 0][m] = v.x; Bsf[lk + 1][m] = v.y; Bsf[lk + 2][m] = v.z; Bsf[lk + 3][m] = v.w;
        }
        __syncthreads();
#pragma unroll
        for (int kk = 0; kk < BK; kk++) {
            float4 A0 = *(const float4*)&Asf[kk][ty * 8];
            float4 A1 = *(const float4*)&Asf[kk][ty * 8 + 4];
            float4 B0 = *(const float4*)&Bsf[kk][tx * 8];
            float4 B1 = *(const float4*)&Bsf[kk][tx * 8 + 4];
            float a[8] = {A0.x, A0.y, A0.z, A0.w, A1.x, A1.y, A1.z, A1.w};
            float b[8] = {B0.x, B0.y, B0.z, B0.w, B1.x, B1.y, B1.z, B1.w};
#pragma unroll
            for (int i = 0; i < 8; i++)
#pragma unroll
                for (int j = 0; j < 8; j++) acc[i][j] = fmaf(a[i], b[j], acc[i][j]);
        }
        __syncthreads();
    }
    unsigned long long best = 0ull;
#pragma unroll
    for (int i = 0; i < 8; i++) {
        int mg = m0 + ty * 8 + i;
        int tl = mg & 1023;
#pragma unroll
        for (int j = 0; j < 8; j++) {
            int kg = n0 + tx * 8 + j;
            float v = acc[i][j] + bias[kg];
            unsigned int c = (unsigned int)(tl * KN + kg);
            unsigned long long p = ((unsigned long long)f32_orderable(v) << 32) |
                                   (unsigned long long)(~c);
            if (p > best) best = p;
        }
    }
#pragma unroll
    for (int off = 32; off > 0; off >>= 1) {
        unsigned long long o = __shfl_down(best, off, 64);
        if (o > best) best = o;
    }
    __shared__ unsigned long long red2[2];
    if ((tid & 63) == 0) red2[tid >> 6] = best;
    __syncthreads();
    if (tid == 0) {
        unsigned long long b0 = red2[0], b1 = red2[1];
        atomicMax(slots + (m0 >> 10), b0 > b1 ? b0 : b1);
    }
}

extern "C" void kernel_launch(void* const* d_in, const int* in_sizes, int n_in,
                              void* d_out, int out_size, void* d_ws, size_t ws_size,
                              hipStream_t stream) {
    const float* X        = (const float*)d_in[0];  // (8,2048,1024)
    const float* W        = (const float*)d_in[1];  // (640,1024)
    const float* bias     = (const float*)d_in[2];  // (640,)
    const float* codebook = (const float*)d_in[3];  // (640,256)
    float* out = (float*)d_out;                     // (8,2048,512) fp32

    unsigned long long* slots = (unsigned long long*)d_ws;   // [0..15] slots, [16] counter
    unsigned int* counter = (unsigned int*)(slots + 16);
    const size_t A_off   = 256;
    const size_t A_bytes = (size_t)MTOT * CC * 2;       // 33,554,432 (hi-only frag-major)
    const size_t B_off   = A_off + A_bytes;
    const size_t B_bytes = (size_t)KN * CC * 2;         // 1,310,720
    const size_t need = B_off + B_bytes;

    if (ws_size >= need) {
        unsigned short* A2F = (unsigned short*)((char*)d_ws + A_off);
        unsigned short* B2F = (unsigned short*)((char*)d_ws + B_off);
        hipLaunchKernelGGL(convert_kernel, dim3(8192 + 320), dim3(256), 0, stream,
                           X, W, A2F, B2F, slots, out);
        hipLaunchKernelGGL(gemm_argmax_mfma, dim3(NBLK), dim3(256), 0, stream,
                           A2F, B2F, X, W, bias, codebook, out, slots, counter);
    } else {
        hipLaunchKernelGGL(init_slots_kernel, dim3(1), dim3(64), 0, stream, slots);
        hipLaunchKernelGGL(gemm_argmax_f32, dim3(KN / BN, MTOT / BM), dim3(128), 0, stream,
                           X, W, bias, slots);
        hipLaunchKernelGGL(zs_kernel, dim3(OUT4 / 256), dim3(256), 0, stream,
                           slots, codebook, (float4*)out);
    }
}